// Round 1
// baseline (426.049 us; speedup 1.0000x reference)
//
#include <hip/hip_runtime.h>
#include <hip/hip_bf16.h>

// ---------------- problem constants ----------------
// B=2 T2=9 T3=27 T1=243 P=17 K2=9 C=128
// CH = {48,96,192,384}, HW = {(96,72),(48,36),(24,18),(12,9)}, N=18
// outputs: new_query [2,243,153,128]=9,517,824 | new_value [2,243,17,128]=1,057,536
//          sampling_positions [18,27,153,2]=148,716
static constexpr int NQ_SIZE = 9517824;
static constexpr int NV_SIZE = 1057536;
static constexpr int NPOS    = 74358;   // 486*153 sampling points

// E-map (projected feature, bf16, channels-last [n,h,w,128]) element offsets in ws
static constexpr long E0_OFF = 0;
static constexpr long E1_OFF = 15925248;            // 18*96*72*128
static constexpr long E2_OFF = E1_OFF + 3981312;    // 18*48*36*128
static constexpr long E3_OFF = E2_OFF + 995328;     // 18*24*18*128
static constexpr long E_END  = E3_OFF + 248832;     // 18*12*9*128  -> 21,150,720 elems

__device__ __forceinline__ float bf2f(unsigned short u) {
    union { unsigned int i; float f; } v; v.i = ((unsigned)u) << 16; return v.f;
}

// ---------------- weight transpose ----------------
// weT_l[k*128+o] = we_l[o*c_l+k]  (concatenated: offsets 0,6144,18432,43008; total 92160)
// convT[(k*128+c)*128+o] = conv_w[o*1152 + c*9 + k]  (147456)
__global__ __launch_bounds__(256) void wtrans_k(
    const float* __restrict__ we0, const float* __restrict__ we1,
    const float* __restrict__ we2, const float* __restrict__ we3,
    const float* __restrict__ conv_w,
    float* __restrict__ weT, float* __restrict__ convT)
{
    int idx = blockIdx.x * 256 + threadIdx.x;
    if (idx < 6144) {
        int k = idx >> 7, o = idx & 127;
        weT[idx] = we0[o * 48 + k];
    } else if (idx < 18432) {
        int r = idx - 6144; int k = r >> 7, o = r & 127;
        weT[idx] = we1[o * 96 + k];
    } else if (idx < 43008) {
        int r = idx - 18432; int k = r >> 7, o = r & 127;
        weT[idx] = we2[o * 192 + k];
    } else if (idx < 92160) {
        int r = idx - 43008; int k = r >> 7, o = r & 127;
        weT[idx] = we3[o * 384 + k];
    } else if (idx < 239616) {
        int r = idx - 92160; int kk = r >> 7, o = r & 127;
        int k = kk >> 7, c = kk & 127;
        convT[r] = conv_w[o * 1152 + c * 9 + k];
    }
}

// ---------------- generic fp32 GEMM, N=128 fixed ----------------
// C[m][o] = sum_k A(k,m) * B[k*128+o] (+bias[o])
// ATRANS=true : A is [K][M], element A[k*lda + m]   (f maps: [c][h*w])
// ATRANS=false: A is [M][K], element A[m*lda + k]   (new_query rows)
// OUTBF16: store bf16 to C (E maps), else fp32.
template<bool ATRANS, bool OUTBF16>
__global__ __launch_bounds__(256) void gemm_k(
    const float* __restrict__ A, int lda, int a_batch,
    const float* __restrict__ B, const float* __restrict__ bias,
    void* __restrict__ Cvoid, int c_batch, int M, int K)
{
    __shared__ float As[16][64];
    __shared__ float Ws[16][128];
    const float* Ab = A + (long)blockIdx.y * a_batch;
    const int m0 = blockIdx.x * 64;
    const int tid = threadIdx.x;
    const int to = tid & 31;       // o = to + 32*oi
    const int tm = tid >> 5;       // m = m0 + tm*8 + mi
    float acc[8][4];
    #pragma unroll
    for (int i = 0; i < 8; ++i)
        #pragma unroll
        for (int j = 0; j < 4; ++j) acc[i][j] = 0.f;

    for (int k0 = 0; k0 < K; k0 += 16) {
        if (ATRANS) {
            int k = tid >> 4;            // 0..15
            int m = (tid & 15) << 2;     // 0..60
            float4 v = {0.f, 0.f, 0.f, 0.f};
            if (m0 + m < M) v = *(const float4*)(Ab + (long)(k0 + k) * lda + m0 + m);
            *(float4*)&As[k][m] = v;
        } else {
            int m = tid >> 2;            // 0..63
            int k = (tid & 3) << 2;      // 0,4,8,12
            float4 v = {0.f, 0.f, 0.f, 0.f};
            if (m0 + m < M) v = *(const float4*)(Ab + (long)(m0 + m) * lda + k0 + k);
            As[k][m] = v.x; As[k + 1][m] = v.y; As[k + 2][m] = v.z; As[k + 3][m] = v.w;
        }
        {
            int k = tid >> 4;
            int o = (tid & 15) << 3;
            const float4* src = (const float4*)(B + (long)(k0 + k) * 128 + o);
            *(float4*)&Ws[k][o]     = src[0];
            *(float4*)&Ws[k][o + 4] = src[1];
        }
        __syncthreads();
        #pragma unroll
        for (int k = 0; k < 16; ++k) {
            float4 a0 = *(const float4*)&As[k][tm * 8];
            float4 a1 = *(const float4*)&As[k][tm * 8 + 4];
            float am[8] = {a0.x, a0.y, a0.z, a0.w, a1.x, a1.y, a1.z, a1.w};
            float wv[4] = {Ws[k][to], Ws[k][to + 32], Ws[k][to + 64], Ws[k][to + 96]};
            #pragma unroll
            for (int mi = 0; mi < 8; ++mi)
                #pragma unroll
                for (int oi = 0; oi < 4; ++oi)
                    acc[mi][oi] = fmaf(am[mi], wv[oi], acc[mi][oi]);
        }
        __syncthreads();
    }

    float bv[4] = {0.f, 0.f, 0.f, 0.f};
    if (bias) { bv[0] = bias[to]; bv[1] = bias[to + 32]; bv[2] = bias[to + 64]; bv[3] = bias[to + 96]; }
    if (OUTBF16) {
        __hip_bfloat16* Cb = (__hip_bfloat16*)Cvoid + (long)blockIdx.y * c_batch;
        #pragma unroll
        for (int mi = 0; mi < 8; ++mi) {
            int m = m0 + tm * 8 + mi;
            if (m < M) {
                #pragma unroll
                for (int oi = 0; oi < 4; ++oi)
                    Cb[(long)m * 128 + to + 32 * oi] = __float2bfloat16(acc[mi][oi] + bv[oi]);
            }
        }
    } else {
        float* Cb = (float*)Cvoid + (long)blockIdx.y * c_batch;
        #pragma unroll
        for (int mi = 0; mi < 8; ++mi) {
            int m = m0 + tm * 8 + mi;
            if (m < M) {
                #pragma unroll
                for (int oi = 0; oi < 4; ++oi)
                    Cb[(long)m * 128 + to + 32 * oi] = acc[mi][oi] + bv[oi];
            }
        }
    }
}

// ---------------- sampling positions ----------------
// per block: one (b,t1). aw = softmax over o of value.w_attn+b_attn (P=17 rows),
// off = tanh(query.w_off+b_off) (153*2), samp = key + off*aw[q%17]
__global__ __launch_bounds__(256) void sampos_k(
    const float* __restrict__ query, const float* __restrict__ value,
    const float* __restrict__ key,
    const float* __restrict__ w_off, const float* __restrict__ b_off,
    const float* __restrict__ w_attn, const float* __restrict__ b_attn,
    float* __restrict__ samp)
{
    const int bt1 = blockIdx.x;          // 0..485  (= b*243 + t1)
    const int b  = bt1 / 243, t1 = bt1 - b * 243;
    const int t2 = t1 / 27,  t3 = t1 - t2 * 27;
    const int n  = b * 9 + t2;
    const int tid = threadIdx.x;
    __shared__ float logit[17][2];
    __shared__ float aw[17][2];

    if (tid < 34) {
        int p = tid >> 1, o = tid & 1;
        const float* vrow = value + ((long)bt1 * 17 + p) * 128;
        const float* wrow = w_attn + o * 128;
        float s = 0.f;
        for (int c = 0; c < 128; c += 4) {
            float4 v = *(const float4*)(vrow + c);
            float4 w = *(const float4*)(wrow + c);
            s += v.x * w.x + v.y * w.y + v.z * w.z + v.w * w.w;
        }
        logit[p][o] = s + b_attn[o];
    }
    __syncthreads();
    if (tid < 17) {
        float l0 = logit[tid][0], l1 = logit[tid][1];
        float mx = fmaxf(l0, l1);
        float e0 = expf(l0 - mx), e1 = expf(l1 - mx);
        float inv = 1.f / (e0 + e1);
        aw[tid][0] = e0 * inv; aw[tid][1] = e1 * inv;
    }
    __syncthreads();
    for (int j = tid; j < 306; j += 256) {
        int q = j >> 1, o = j & 1;
        const float* qrow = query + ((long)bt1 * 153 + q) * 128;
        const float* wrow = w_off + o * 128;
        float s = 0.f;
        for (int c = 0; c < 128; c += 4) {
            float4 v = *(const float4*)(qrow + c);
            float4 w = *(const float4*)(wrow + c);
            s += v.x * w.x + v.y * w.y + v.z * w.z + v.w * w.w;
        }
        float off = tanhf(s + b_off[o]);
        float sp = off * aw[q % 17][o];
        long kidx = (((long)n * 27 + t3) * 153 + q) * 2 + o;
        samp[kidx] = key[kidx] + sp;
    }
}

// ---------------- gather + mean + blend -> new_query ----------------
// 8 positions/block, 32 lanes/position, 4 channels/lane (float4).
__global__ __launch_bounds__(256) void gather_k(
    const unsigned short* __restrict__ Ebase,
    const float* __restrict__ samp, const float* __restrict__ query,
    const float* __restrict__ be0, const float* __restrict__ be1,
    const float* __restrict__ be2, const float* __restrict__ be3,
    float* __restrict__ nq)
{
    const int tid = threadIdx.x;
    const int pos = blockIdx.x * 8 + (tid >> 5);
    if (pos >= NPOS) return;
    const int c4 = (tid & 31) << 2;
    const int bt1 = pos / 153, q = pos - bt1 * 153;
    const int b  = bt1 / 243, t1 = bt1 - b * 243;
    const int t2 = t1 / 27,  t3 = t1 - t2 * 27;
    const int n  = b * 9 + t2;
    const long sbase = (((long)n * 27 + t3) * 153 + q) * 2;
    const float gx = samp[sbase], gy = samp[sbase + 1];

    float ax = 0.f, ay = 0.f, az = 0.f, aww = 0.f;
    const long Eoffs[4] = {E0_OFF, E1_OFF, E2_OFF, E3_OFF};
    const int Hs[4] = {96, 48, 24, 12}, Wd[4] = {72, 36, 18, 9};
    #pragma unroll
    for (int l = 0; l < 4; ++l) {
        const int H = Hs[l], W = Wd[l];
        const unsigned short* E = Ebase + Eoffs[l] + (long)n * H * W * 128 + c4;
        float ix = ((gx + 1.f) * (float)W - 1.f) * 0.5f;
        float iy = ((gy + 1.f) * (float)H - 1.f) * 0.5f;
        float fx0 = floorf(ix), fy0 = floorf(iy);
        int x0 = (int)fx0, y0 = (int)fy0;
        int x1 = x0 + 1, y1 = y0 + 1;
        float wx1 = ix - fx0, wx0 = 1.f - wx1;
        float wy1 = iy - fy0, wy0 = 1.f - wy1;
        float w00 = wy0 * wx0, w01 = wy0 * wx1, w10 = wy1 * wx0, w11 = wy1 * wx1;
        bool vy0 = (unsigned)y0 < (unsigned)H, vy1 = (unsigned)y1 < (unsigned)H;
        bool vx0 = (unsigned)x0 < (unsigned)W, vx1 = (unsigned)x1 < (unsigned)W;
        if (vy0 && vx0) { ushort4 v = *(const ushort4*)(E + ((long)y0 * W + x0) * 128);
            ax = fmaf(w00, bf2f(v.x), ax); ay = fmaf(w00, bf2f(v.y), ay);
            az = fmaf(w00, bf2f(v.z), az); aww = fmaf(w00, bf2f(v.w), aww); }
        if (vy0 && vx1) { ushort4 v = *(const ushort4*)(E + ((long)y0 * W + x1) * 128);
            ax = fmaf(w01, bf2f(v.x), ax); ay = fmaf(w01, bf2f(v.y), ay);
            az = fmaf(w01, bf2f(v.z), az); aww = fmaf(w01, bf2f(v.w), aww); }
        if (vy1 && vx0) { ushort4 v = *(const ushort4*)(E + ((long)y1 * W + x0) * 128);
            ax = fmaf(w10, bf2f(v.x), ax); ay = fmaf(w10, bf2f(v.y), ay);
            az = fmaf(w10, bf2f(v.z), az); aww = fmaf(w10, bf2f(v.w), aww); }
        if (vy1 && vx1) { ushort4 v = *(const ushort4*)(E + ((long)y1 * W + x1) * 128);
            ax = fmaf(w11, bf2f(v.x), ax); ay = fmaf(w11, bf2f(v.y), ay);
            az = fmaf(w11, bf2f(v.z), az); aww = fmaf(w11, bf2f(v.w), aww); }
    }
    // mean over 4 levels; each level's bias be_l added once per sample (not tap-weighted)
    float bsx = be0[c4]     + be1[c4]     + be2[c4]     + be3[c4];
    float bsy = be0[c4 + 1] + be1[c4 + 1] + be2[c4 + 1] + be3[c4 + 1];
    float bsz = be0[c4 + 2] + be1[c4 + 2] + be2[c4 + 2] + be3[c4 + 2];
    float bsw = be0[c4 + 3] + be1[c4 + 3] + be2[c4 + 3] + be3[c4 + 3];
    float mx = 0.25f * (ax + bsx), my = 0.25f * (ay + bsy);
    float mz = 0.25f * (az + bsz), mw = 0.25f * (aww + bsw);
    const long qi = ((long)bt1 * 153 + q) * 128 + c4;
    float4 qv = *(const float4*)(query + qi);
    float4 o;
    o.x = 0.1f * mx + 0.9f * qv.x;
    o.y = 0.1f * my + 0.9f * qv.y;
    o.z = 0.1f * mz + 0.9f * qv.z;
    o.w = 0.1f * mw + 0.9f * qv.w;
    *(float4*)(nq + qi) = o;
}

extern "C" void kernel_launch(void* const* d_in, const int* in_sizes, int n_in,
                              void* d_out, int out_size, void* d_ws, size_t ws_size,
                              hipStream_t stream) {
    const float* f0     = (const float*)d_in[0];
    const float* f1     = (const float*)d_in[1];
    const float* f2     = (const float*)d_in[2];
    const float* f3     = (const float*)d_in[3];
    const float* query  = (const float*)d_in[4];
    const float* key    = (const float*)d_in[5];
    const float* value  = (const float*)d_in[6];
    const float* w_off  = (const float*)d_in[7];
    const float* b_off  = (const float*)d_in[8];
    const float* w_attn = (const float*)d_in[9];
    const float* b_attn = (const float*)d_in[10];
    const float* we0    = (const float*)d_in[11];
    const float* be0    = (const float*)d_in[12];
    const float* we1    = (const float*)d_in[13];
    const float* be1    = (const float*)d_in[14];
    const float* we2    = (const float*)d_in[15];
    const float* be2    = (const float*)d_in[16];
    const float* we3    = (const float*)d_in[17];
    const float* be3    = (const float*)d_in[18];
    const float* conv_w = (const float*)d_in[19];
    const float* conv_b = (const float*)d_in[20];

    float* out  = (float*)d_out;
    float* nq   = out;                       // new_query
    float* nv   = out + NQ_SIZE;             // new_value
    float* samp = out + NQ_SIZE + NV_SIZE;   // sampling_positions

    // ws layout: E maps (bf16, 21,150,720 elems = 42.3 MB) then fp32 weT/convT
    unsigned short* Ebase = (unsigned short*)d_ws;
    float* weT   = (float*)((char*)d_ws + E_END * sizeof(unsigned short));
    float* convT = weT + 92160;

    // 1. weight transposes
    wtrans_k<<<(239616 + 255) / 256, 256, 0, stream>>>(we0, we1, we2, we3, conv_w, weT, convT);

    // 2. projection GEMMs: E_l[n,s,o] = sum_c f_l[n,c,s]*we_l[o,c]   (bias added later)
    gemm_k<true, true><<<dim3(108, 18), 256, 0, stream>>>(f0, 6912, 48 * 6912,  weT,         nullptr,
        (void*)(Ebase + E0_OFF), 6912 * 128, 6912, 48);
    gemm_k<true, true><<<dim3(27, 18), 256, 0, stream>>>(f1, 1728, 96 * 1728,  weT + 6144,  nullptr,
        (void*)(Ebase + E1_OFF), 1728 * 128, 1728, 96);
    gemm_k<true, true><<<dim3(7, 18), 256, 0, stream>>>(f2, 432,  192 * 432,  weT + 18432, nullptr,
        (void*)(Ebase + E2_OFF), 432 * 128, 432, 192);
    gemm_k<true, true><<<dim3(2, 18), 256, 0, stream>>>(f3, 108,  384 * 108,  weT + 43008, nullptr,
        (void*)(Ebase + E3_OFF), 108 * 128, 108, 384);

    // 3. sampling positions
    sampos_k<<<486, 256, 0, stream>>>(query, value, key, w_off, b_off, w_attn, b_attn, samp);

    // 4. gather + mean + blend -> new_query
    gather_k<<<(NPOS + 7) / 8, 256, 0, stream>>>(Ebase, samp, query, be0, be1, be2, be3, nq);

    // 5. new_value GEMM: M=8262 rows (contiguous, lda=1152), K=1152, N=128
    gemm_k<false, false><<<dim3(130, 1), 256, 0, stream>>>(nq, 1152, 0, convT, conv_b,
        (void*)nv, 0, 8262, 1152);
}

// Round 2
// 344.435 us; speedup vs baseline: 1.2369x; 1.2369x over previous
//
#include <hip/hip_runtime.h>
#include <hip/hip_bf16.h>

// ---------------- problem constants ----------------
// B=2 T2=9 T3=27 T1=243 P=17 K2=9 C=128
// CH = {48,96,192,384}, HW = {(96,72),(48,36),(24,18),(12,9)}, N=18
static constexpr int NQ_SIZE = 9517824;
static constexpr int NV_SIZE = 1057536;
static constexpr int NPOS    = 74358;   // 486*153 sampling points
static constexpr int M_CONV  = 8262;    // 2*243*17 rows of the conv GEMM

// E-map (projected feature, bf16, channels-last [n,h,w,128]) element offsets in ws
static constexpr long E0_OFF = 0;
static constexpr long E1_OFF = 15925248;            // 18*96*72*128
static constexpr long E2_OFF = E1_OFF + 3981312;    // 18*48*36*128
static constexpr long E3_OFF = E2_OFF + 995328;     // 18*24*18*128
static constexpr long E_END  = E3_OFF + 248832;     // 18*12*9*128  -> 21,150,720 elems

typedef __attribute__((ext_vector_type(8))) short short8;   // 8 bf16 (4 VGPRs)
typedef __attribute__((ext_vector_type(4))) float floatx4;

__device__ __forceinline__ float bf2f(unsigned short u) {
    union { unsigned int i; float f; } v; v.i = ((unsigned)u) << 16; return v.f;
}
__device__ __forceinline__ unsigned short f2bf_rne(float f) {
    union { float f; unsigned int i; } v; v.f = f;
    unsigned int u = v.i;
    u += 0x7fffu + ((u >> 16) & 1u);
    return (unsigned short)(u >> 16);
}

// ---------------- weight transpose ----------------
// weT_l[k*128+o] = we_l[o*c_l+k]  (fp32; offsets 0,6144,18432,43008; total 92160)
// convT2[o*1152 + (k2*128+c)] = bf16(conv_w[o*1152 + c*9 + k2])  (bf16, 147456)
__global__ __launch_bounds__(256) void wtrans_k(
    const float* __restrict__ we0, const float* __restrict__ we1,
    const float* __restrict__ we2, const float* __restrict__ we3,
    const float* __restrict__ conv_w,
    float* __restrict__ weT, unsigned short* __restrict__ convT2)
{
    int idx = blockIdx.x * 256 + threadIdx.x;
    if (idx < 6144) {
        int k = idx >> 7, o = idx & 127;
        weT[idx] = we0[o * 48 + k];
    } else if (idx < 18432) {
        int r = idx - 6144; int k = r >> 7, o = r & 127;
        weT[idx] = we1[o * 96 + k];
    } else if (idx < 43008) {
        int r = idx - 18432; int k = r >> 7, o = r & 127;
        weT[idx] = we2[o * 192 + k];
    } else if (idx < 92160) {
        int r = idx - 43008; int k = r >> 7, o = r & 127;
        weT[idx] = we3[o * 384 + k];
    } else if (idx < 239616) {
        int r = idx - 92160;
        int o = r / 1152, kk = r - o * 1152;
        int k2 = kk >> 7, c = kk & 127;
        convT2[r] = f2bf_rne(conv_w[o * 1152 + c * 9 + k2]);
    }
}

// ---------------- generic fp32 GEMM, N=128 fixed (projection GEMMs) ----------------
// C[m][o] = sum_k A[k*lda+m] * B[k*128+o]; bf16 out.
__global__ __launch_bounds__(256) void gemm_k(
    const float* __restrict__ A, int lda, int a_batch,
    const float* __restrict__ B,
    unsigned short* __restrict__ Cb16, int c_batch, int M, int K)
{
    __shared__ float As[16][64];
    __shared__ float Ws[16][128];
    const float* Ab = A + (long)blockIdx.y * a_batch;
    const int m0 = blockIdx.x * 64;
    const int tid = threadIdx.x;
    const int to = tid & 31;
    const int tm = tid >> 5;
    float acc[8][4];
    #pragma unroll
    for (int i = 0; i < 8; ++i)
        #pragma unroll
        for (int j = 0; j < 4; ++j) acc[i][j] = 0.f;

    for (int k0 = 0; k0 < K; k0 += 16) {
        {
            int k = tid >> 4;            // 0..15
            int m = (tid & 15) << 2;     // 0..60
            float4 v = {0.f, 0.f, 0.f, 0.f};
            if (m0 + m < M) v = *(const float4*)(Ab + (long)(k0 + k) * lda + m0 + m);
            *(float4*)&As[k][m] = v;
        }
        {
            int k = tid >> 4;
            int o = (tid & 15) << 3;
            const float4* src = (const float4*)(B + (long)(k0 + k) * 128 + o);
            *(float4*)&Ws[k][o]     = src[0];
            *(float4*)&Ws[k][o + 4] = src[1];
        }
        __syncthreads();
        #pragma unroll
        for (int k = 0; k < 16; ++k) {
            float4 a0 = *(const float4*)&As[k][tm * 8];
            float4 a1 = *(const float4*)&As[k][tm * 8 + 4];
            float am[8] = {a0.x, a0.y, a0.z, a0.w, a1.x, a1.y, a1.z, a1.w};
            float wv[4] = {Ws[k][to], Ws[k][to + 32], Ws[k][to + 64], Ws[k][to + 96]};
            #pragma unroll
            for (int mi = 0; mi < 8; ++mi)
                #pragma unroll
                for (int oi = 0; oi < 4; ++oi)
                    acc[mi][oi] = fmaf(am[mi], wv[oi], acc[mi][oi]);
        }
        __syncthreads();
    }

    unsigned short* Cp = Cb16 + (long)blockIdx.y * c_batch;
    #pragma unroll
    for (int mi = 0; mi < 8; ++mi) {
        int m = m0 + tm * 8 + mi;
        if (m < M) {
            #pragma unroll
            for (int oi = 0; oi < 4; ++oi)
                Cp[(long)m * 128 + to + 32 * oi] = f2bf_rne(acc[mi][oi]);
        }
    }
}

// ---------------- sampling positions ----------------
__global__ __launch_bounds__(256) void sampos_k(
    const float* __restrict__ query, const float* __restrict__ value,
    const float* __restrict__ key,
    const float* __restrict__ w_off, const float* __restrict__ b_off,
    const float* __restrict__ w_attn, const float* __restrict__ b_attn,
    float* __restrict__ samp)
{
    const int bt1 = blockIdx.x;          // 0..485
    const int b  = bt1 / 243, t1 = bt1 - b * 243;
    const int t2 = t1 / 27,  t3 = t1 - t2 * 27;
    const int n  = b * 9 + t2;
    const int tid = threadIdx.x;
    __shared__ float logit[17][2];
    __shared__ float aw[17][2];

    if (tid < 34) {
        int p = tid >> 1, o = tid & 1;
        const float* vrow = value + ((long)bt1 * 17 + p) * 128;
        const float* wrow = w_attn + o * 128;
        float s = 0.f;
        for (int c = 0; c < 128; c += 4) {
            float4 v = *(const float4*)(vrow + c);
            float4 w = *(const float4*)(wrow + c);
            s += v.x * w.x + v.y * w.y + v.z * w.z + v.w * w.w;
        }
        logit[p][o] = s + b_attn[o];
    }
    __syncthreads();
    if (tid < 17) {
        float l0 = logit[tid][0], l1 = logit[tid][1];
        float mx = fmaxf(l0, l1);
        float e0 = expf(l0 - mx), e1 = expf(l1 - mx);
        float inv = 1.f / (e0 + e1);
        aw[tid][0] = e0 * inv; aw[tid][1] = e1 * inv;
    }
    __syncthreads();
    for (int j = tid; j < 306; j += 256) {
        int q = j >> 1, o = j & 1;
        const float* qrow = query + ((long)bt1 * 153 + q) * 128;
        const float* wrow = w_off + o * 128;
        float s = 0.f;
        for (int c = 0; c < 128; c += 4) {
            float4 v = *(const float4*)(qrow + c);
            float4 w = *(const float4*)(wrow + c);
            s += v.x * w.x + v.y * w.y + v.z * w.z + v.w * w.w;
        }
        float off = tanhf(s + b_off[o]);
        float sp = off * aw[q % 17][o];
        long kidx = (((long)n * 27 + t3) * 153 + q) * 2 + o;
        samp[kidx] = key[kidx] + sp;
    }
}

// ---------------- gather + mean + blend -> new_query ----------------
__global__ __launch_bounds__(256) void gather_k(
    const unsigned short* __restrict__ Ebase,
    const float* __restrict__ samp, const float* __restrict__ query,
    const float* __restrict__ be0, const float* __restrict__ be1,
    const float* __restrict__ be2, const float* __restrict__ be3,
    float* __restrict__ nq)
{
    const int tid = threadIdx.x;
    const int pos = blockIdx.x * 8 + (tid >> 5);
    if (pos >= NPOS) return;
    const int c4 = (tid & 31) << 2;
    const int bt1 = pos / 153, q = pos - bt1 * 153;
    const int b  = bt1 / 243, t1 = bt1 - b * 243;
    const int t2 = t1 / 27,  t3 = t1 - t2 * 27;
    const int n  = b * 9 + t2;
    const long sbase = (((long)n * 27 + t3) * 153 + q) * 2;
    const float gx = samp[sbase], gy = samp[sbase + 1];

    float ax = 0.f, ay = 0.f, az = 0.f, aww = 0.f;
    const long Eoffs[4] = {E0_OFF, E1_OFF, E2_OFF, E3_OFF};
    const int Hs[4] = {96, 48, 24, 12}, Wd[4] = {72, 36, 18, 9};
    #pragma unroll
    for (int l = 0; l < 4; ++l) {
        const int H = Hs[l], W = Wd[l];
        const unsigned short* E = Ebase + Eoffs[l] + (long)n * H * W * 128 + c4;
        float ix = ((gx + 1.f) * (float)W - 1.f) * 0.5f;
        float iy = ((gy + 1.f) * (float)H - 1.f) * 0.5f;
        float fx0 = floorf(ix), fy0 = floorf(iy);
        int x0 = (int)fx0, y0 = (int)fy0;
        int x1 = x0 + 1, y1 = y0 + 1;
        float wx1 = ix - fx0, wx0 = 1.f - wx1;
        float wy1 = iy - fy0, wy0 = 1.f - wy1;
        float w00 = wy0 * wx0, w01 = wy0 * wx1, w10 = wy1 * wx0, w11 = wy1 * wx1;
        bool vy0 = (unsigned)y0 < (unsigned)H, vy1 = (unsigned)y1 < (unsigned)H;
        bool vx0 = (unsigned)x0 < (unsigned)W, vx1 = (unsigned)x1 < (unsigned)W;
        if (vy0 && vx0) { ushort4 v = *(const ushort4*)(E + ((long)y0 * W + x0) * 128);
            ax = fmaf(w00, bf2f(v.x), ax); ay = fmaf(w00, bf2f(v.y), ay);
            az = fmaf(w00, bf2f(v.z), az); aww = fmaf(w00, bf2f(v.w), aww); }
        if (vy0 && vx1) { ushort4 v = *(const ushort4*)(E + ((long)y0 * W + x1) * 128);
            ax = fmaf(w01, bf2f(v.x), ax); ay = fmaf(w01, bf2f(v.y), ay);
            az = fmaf(w01, bf2f(v.z), az); aww = fmaf(w01, bf2f(v.w), aww); }
        if (vy1 && vx0) { ushort4 v = *(const ushort4*)(E + ((long)y1 * W + x0) * 128);
            ax = fmaf(w10, bf2f(v.x), ax); ay = fmaf(w10, bf2f(v.y), ay);
            az = fmaf(w10, bf2f(v.z), az); aww = fmaf(w10, bf2f(v.w), aww); }
        if (vy1 && vx1) { ushort4 v = *(const ushort4*)(E + ((long)y1 * W + x1) * 128);
            ax = fmaf(w11, bf2f(v.x), ax); ay = fmaf(w11, bf2f(v.y), ay);
            az = fmaf(w11, bf2f(v.z), az); aww = fmaf(w11, bf2f(v.w), aww); }
    }
    float bsx = be0[c4]     + be1[c4]     + be2[c4]     + be3[c4];
    float bsy = be0[c4 + 1] + be1[c4 + 1] + be2[c4 + 1] + be3[c4 + 1];
    float bsz = be0[c4 + 2] + be1[c4 + 2] + be2[c4 + 2] + be3[c4 + 2];
    float bsw = be0[c4 + 3] + be1[c4 + 3] + be2[c4 + 3] + be3[c4 + 3];
    float mx = 0.25f * (ax + bsx), my = 0.25f * (ay + bsy);
    float mz = 0.25f * (az + bsz), mw = 0.25f * (aww + bsw);
    const long qi = ((long)bt1 * 153 + q) * 128 + c4;
    float4 qv = *(const float4*)(query + qi);
    float4 o;
    o.x = 0.1f * mx + 0.9f * qv.x;
    o.y = 0.1f * my + 0.9f * qv.y;
    o.z = 0.1f * mz + 0.9f * qv.z;
    o.w = 0.1f * mw + 0.9f * qv.w;
    *(float4*)(nq + qi) = o;
}

// ---------------- conv GEMM via bf16 MFMA ----------------
// nv[m][o] = sum_kk nq[m*1152+kk] * convT2[o][kk] + conv_b[o]
// block = 256 (4 waves, 2x2), tile M=64 x N=128, BK=32, 16x16x32 bf16 MFMA.
// A (fp32 nq) converted to bf16 during LDS staging.
__global__ __launch_bounds__(256) void conv_mfma_k(
    const float* __restrict__ nq, const unsigned short* __restrict__ convT2,
    const float* __restrict__ conv_b, float* __restrict__ nv)
{
    __shared__ unsigned short As[64][40];   // [m][k] pad 32->40 (row 80B, 16B-aligned)
    __shared__ unsigned short Bs[128][40];  // [n][k]

    const int tid  = threadIdx.x;
    const int lane = tid & 63;
    const int wave = tid >> 6;
    const int wm = (wave & 1) * 32;
    const int wn = (wave >> 1) * 64;
    const int m0 = blockIdx.x * 64;
    const int l15  = lane & 15;
    const int quad = lane >> 4;

    floatx4 acc[2][4];
    #pragma unroll
    for (int i = 0; i < 2; ++i)
        #pragma unroll
        for (int j = 0; j < 4; ++j) acc[i][j] = (floatx4){0.f, 0.f, 0.f, 0.f};

    // staging indices
    const int am = tid >> 2;             // 0..63
    const int ak = (tid & 3) << 3;       // 0,8,16,24
    const int bn = tid & 127;            // 0..127
    const int bk = (tid >> 7) << 4;      // 0,16

    for (int k0 = 0; k0 < 1152; k0 += 32) {
        // A: 64 rows x 32 k, fp32 -> bf16
        {
            int row = m0 + am;
            float4 v0 = {0,0,0,0}, v1 = {0,0,0,0};
            if (row < M_CONV) {
                const float* p = nq + (long)row * 1152 + k0 + ak;
                v0 = *(const float4*)p;
                v1 = *(const float4*)(p + 4);
            }
            unsigned short* dst = &As[am][ak];
            dst[0] = f2bf_rne(v0.x); dst[1] = f2bf_rne(v0.y);
            dst[2] = f2bf_rne(v0.z); dst[3] = f2bf_rne(v0.w);
            dst[4] = f2bf_rne(v1.x); dst[5] = f2bf_rne(v1.y);
            dst[6] = f2bf_rne(v1.z); dst[7] = f2bf_rne(v1.w);
        }
        // B: 128 rows x 32 k, bf16 direct
        {
            const unsigned short* src = convT2 + (long)bn * 1152 + k0 + bk;
            uint4 v0 = *(const uint4*)src;
            uint4 v1 = *(const uint4*)(src + 8);
            *(uint4*)&Bs[bn][bk]     = v0;
            *(uint4*)&Bs[bn][bk + 8] = v1;
        }
        __syncthreads();

        short8 af[2], bfr[4];
        #pragma unroll
        for (int mt = 0; mt < 2; ++mt)
            af[mt] = *(const short8*)&As[wm + mt * 16 + l15][quad * 8];
        #pragma unroll
        for (int nt = 0; nt < 4; ++nt)
            bfr[nt] = *(const short8*)&Bs[wn + nt * 16 + l15][quad * 8];
        #pragma unroll
        for (int mt = 0; mt < 2; ++mt)
            #pragma unroll
            for (int nt = 0; nt < 4; ++nt)
                acc[mt][nt] = __builtin_amdgcn_mfma_f32_16x16x32_bf16(
                    af[mt], bfr[nt], acc[mt][nt], 0, 0, 0);
        __syncthreads();
    }

    // epilogue: C/D layout col=lane&15, row=quad*4+r
    #pragma unroll
    for (int mt = 0; mt < 2; ++mt) {
        #pragma unroll
        for (int nt = 0; nt < 4; ++nt) {
            int col = wn + nt * 16 + l15;
            float bias = conv_b[col];
            #pragma unroll
            for (int r = 0; r < 4; ++r) {
                int row = m0 + wm + mt * 16 + quad * 4 + r;
                if (row < M_CONV)
                    nv[(long)row * 128 + col] = acc[mt][nt][r] + bias;
            }
        }
    }
}

extern "C" void kernel_launch(void* const* d_in, const int* in_sizes, int n_in,
                              void* d_out, int out_size, void* d_ws, size_t ws_size,
                              hipStream_t stream) {
    const float* f0     = (const float*)d_in[0];
    const float* f1     = (const float*)d_in[1];
    const float* f2     = (const float*)d_in[2];
    const float* f3     = (const float*)d_in[3];
    const float* query  = (const float*)d_in[4];
    const float* key    = (const float*)d_in[5];
    const float* value  = (const float*)d_in[6];
    const float* w_off  = (const float*)d_in[7];
    const float* b_off  = (const float*)d_in[8];
    const float* w_attn = (const float*)d_in[9];
    const float* b_attn = (const float*)d_in[10];
    const float* we0    = (const float*)d_in[11];
    const float* be0    = (const float*)d_in[12];
    const float* we1    = (const float*)d_in[13];
    const float* be1    = (const float*)d_in[14];
    const float* we2    = (const float*)d_in[15];
    const float* be2    = (const float*)d_in[16];
    const float* we3    = (const float*)d_in[17];
    const float* be3    = (const float*)d_in[18];
    const float* conv_w = (const float*)d_in[19];
    const float* conv_b = (const float*)d_in[20];

    float* out  = (float*)d_out;
    float* nq   = out;                       // new_query
    float* nv   = out + NQ_SIZE;             // new_value
    float* samp = out + NQ_SIZE + NV_SIZE;   // sampling_positions

    // ws layout: E maps (bf16) | weT (fp32, 92160) | convT2 (bf16, 147456)
    unsigned short* Ebase = (unsigned short*)d_ws;
    float* weT = (float*)((char*)d_ws + E_END * sizeof(unsigned short));
    unsigned short* convT2 = (unsigned short*)(weT + 92160);

    // 1. weight transposes / dtype prep
    wtrans_k<<<(239616 + 255) / 256, 256, 0, stream>>>(we0, we1, we2, we3, conv_w, weT, convT2);

    // 2. projection GEMMs: E_l[n,s,o] = sum_c f_l[n,c,s]*we_l[o,c]
    gemm_k<<<dim3(108, 18), 256, 0, stream>>>(f0, 6912, 48 * 6912,  weT,
        Ebase + E0_OFF, 6912 * 128, 6912, 48);
    gemm_k<<<dim3(27, 18), 256, 0, stream>>>(f1, 1728, 96 * 1728,  weT + 6144,
        Ebase + E1_OFF, 1728 * 128, 1728, 96);
    gemm_k<<<dim3(7, 18), 256, 0, stream>>>(f2, 432,  192 * 432,  weT + 18432,
        Ebase + E2_OFF, 432 * 128, 432, 192);
    gemm_k<<<dim3(2, 18), 256, 0, stream>>>(f3, 108,  384 * 108,  weT + 43008,
        Ebase + E3_OFF, 108 * 128, 108, 384);

    // 3. sampling positions
    sampos_k<<<486, 256, 0, stream>>>(query, value, key, w_off, b_off, w_attn, b_attn, samp);

    // 4. gather + mean + blend -> new_query
    gather_k<<<(NPOS + 7) / 8, 256, 0, stream>>>(Ebase, samp, query, be0, be1, be2, be3, nq);

    // 5. new_value GEMM via MFMA: M=8262, K=1152, N=128
    conv_mfma_k<<<130, 256, 0, stream>>>(nq, convT2, conv_b, nv);
}

// Round 3
// 265.097 us; speedup vs baseline: 1.6071x; 1.2993x over previous
//
#include <hip/hip_runtime.h>
#include <hip/hip_bf16.h>

// ---------------- problem constants ----------------
// B=2 T2=9 T3=27 T1=243 P=17 K2=9 C=128
// CH = {48,96,192,384}, HW = {(96,72),(48,36),(24,18),(12,9)}, N=18
static constexpr int NQ_SIZE = 9517824;
static constexpr int NV_SIZE = 1057536;
static constexpr int NPOS    = 74358;   // 486*153 sampling points
static constexpr int M_CONV  = 8262;    // 2*243*17 rows of the conv GEMM

// E-map (projected feature, bf16, channels-last [n,h,w,128]) element offsets in ws
static constexpr long E0_OFF = 0;
static constexpr long E1_OFF = 15925248;            // 18*96*72*128
static constexpr long E2_OFF = E1_OFF + 3981312;    // 18*48*36*128
static constexpr long E3_OFF = E2_OFF + 995328;     // 18*24*18*128
static constexpr long E_END  = E3_OFF + 248832;     // 18*12*9*128  -> 21,150,720 elems

// prep kernel block-range segmentation (long-serial levels first)
static constexpr int SEG_F3  = 36;            // 2 tiles x 18
static constexpr int SEG_F2  = SEG_F3 + 126;  // 7 x 18
static constexpr int SEG_F1  = SEG_F2 + 486;  // 27 x 18
static constexpr int SEG_F0  = SEG_F1 + 1944; // 108 x 18
static constexpr int SEG_CT  = SEG_F0 + 576;  // convT2: 147456/256
static constexpr int SEG_SP  = SEG_CT + 486;  // sampos
static constexpr int PREP_GRID = SEG_SP;      // 3654

typedef __attribute__((ext_vector_type(8))) short short8;   // 8 bf16 (4 VGPRs)
typedef __attribute__((ext_vector_type(4))) float floatx4;

__device__ __forceinline__ float bf2f(unsigned short u) {
    union { unsigned int i; float f; } v; v.i = ((unsigned)u) << 16; return v.f;
}
__device__ __forceinline__ unsigned short f2bf_rne(float f) {
    union { float f; unsigned int i; } v; v.f = f;
    unsigned int u = v.i;
    u += 0x7fffu + ((u >> 16) & 1u);
    return (unsigned short)(u >> 16);
}

// ---------------- fused prep kernel ----------------
// blocks [0,SEG_F0):   projection GEMMs  E_l[n,s,o] = sum_c f_l[n,c,s]*we_l[o,c]
//                      (B transposed from we during staging; reg double-buffer)
// blocks [SEG_F0,SEG_CT): convT2[o*1152+(k2*128+c)] = bf16(conv_w[o*1152+c*9+k2])
// blocks [SEG_CT,SEG_SP): sampling positions
__global__ __launch_bounds__(256) void prep_k(
    const float* __restrict__ f0, const float* __restrict__ f1,
    const float* __restrict__ f2, const float* __restrict__ f3,
    const float* __restrict__ we0, const float* __restrict__ we1,
    const float* __restrict__ we2, const float* __restrict__ we3,
    const float* __restrict__ conv_w, unsigned short* __restrict__ convT2,
    const float* __restrict__ query, const float* __restrict__ value,
    const float* __restrict__ key,
    const float* __restrict__ w_off, const float* __restrict__ b_off,
    const float* __restrict__ w_attn, const float* __restrict__ b_attn,
    float* __restrict__ samp, unsigned short* __restrict__ Ebase)
{
    const int bid = blockIdx.x;
    const int tid = threadIdx.x;

    if (bid < SEG_F0) {
        // ---- projection GEMM tile: 64 m x 128 o, BK=16, fp32 FMA ----
        __shared__ float As[16][64];
        __shared__ float Ws[16][128];
        const float* A; const float* W; unsigned short* Eo;
        int M, K, m0;
        if (bid < SEG_F3) {
            int n = bid >> 1, t = bid & 1;
            M = 108; K = 384; A = f3 + (long)n * 384 * 108; W = we3;
            Eo = Ebase + E3_OFF + (long)n * 108 * 128; m0 = t * 64;
        } else if (bid < SEG_F2) {
            int r = bid - SEG_F3; int n = r / 7, t = r - n * 7;
            M = 432; K = 192; A = f2 + (long)n * 192 * 432; W = we2;
            Eo = Ebase + E2_OFF + (long)n * 432 * 128; m0 = t * 64;
        } else if (bid < SEG_F1) {
            int r = bid - SEG_F2; int n = r / 27, t = r - n * 27;
            M = 1728; K = 96; A = f1 + (long)n * 96 * 1728; W = we1;
            Eo = Ebase + E1_OFF + (long)n * 1728 * 128; m0 = t * 64;
        } else {
            int r = bid - SEG_F1; int n = r / 108, t = r - n * 108;
            M = 6912; K = 48; A = f0 + (long)n * 48 * 6912; W = we0;
            Eo = Ebase + E0_OFF + (long)n * 6912 * 128; m0 = t * 64;
        }

        const int to = tid & 31;       // o = to + 32*oi
        const int tm = tid >> 5;       // m = m0 + tm*8 + mi
        const int sk = tid >> 4;       // A staging: k 0..15
        const int sm = (tid & 15) << 2;// A staging: m offset
        const int bo = tid >> 1;       // B staging: o 0..127
        const int bh = (tid & 1) << 3; // B staging: k half 0/8

        float acc[8][4];
        #pragma unroll
        for (int i = 0; i < 8; ++i)
            #pragma unroll
            for (int j = 0; j < 4; ++j) acc[i][j] = 0.f;

        float4 a_pf, b_pf0, b_pf1;
        auto fetch = [&](int k0) {
            a_pf = (float4){0.f, 0.f, 0.f, 0.f};
            if (m0 + sm < M)
                a_pf = *(const float4*)(A + (long)(k0 + sk) * M + m0 + sm);
            const float* wp = W + (long)bo * K + k0 + bh;
            b_pf0 = *(const float4*)wp;
            b_pf1 = *(const float4*)(wp + 4);
        };
        fetch(0);

        for (int k0 = 0; k0 < K; k0 += 16) {
            *(float4*)&As[sk][sm] = a_pf;
            Ws[bh + 0][bo] = b_pf0.x; Ws[bh + 1][bo] = b_pf0.y;
            Ws[bh + 2][bo] = b_pf0.z; Ws[bh + 3][bo] = b_pf0.w;
            Ws[bh + 4][bo] = b_pf1.x; Ws[bh + 5][bo] = b_pf1.y;
            Ws[bh + 6][bo] = b_pf1.z; Ws[bh + 7][bo] = b_pf1.w;
            __syncthreads();
            if (k0 + 16 < K) fetch(k0 + 16);
            #pragma unroll
            for (int k = 0; k < 16; ++k) {
                float4 a0 = *(const float4*)&As[k][tm * 8];
                float4 a1 = *(const float4*)&As[k][tm * 8 + 4];
                float am[8] = {a0.x, a0.y, a0.z, a0.w, a1.x, a1.y, a1.z, a1.w};
                float wv[4] = {Ws[k][to], Ws[k][to + 32], Ws[k][to + 64], Ws[k][to + 96]};
                #pragma unroll
                for (int mi = 0; mi < 8; ++mi)
                    #pragma unroll
                    for (int oi = 0; oi < 4; ++oi)
                        acc[mi][oi] = fmaf(am[mi], wv[oi], acc[mi][oi]);
            }
            __syncthreads();
        }

        #pragma unroll
        for (int mi = 0; mi < 8; ++mi) {
            int m = m0 + tm * 8 + mi;
            if (m < M) {
                #pragma unroll
                for (int oi = 0; oi < 4; ++oi)
                    Eo[(long)m * 128 + to + 32 * oi] = f2bf_rne(acc[mi][oi]);
            }
        }
    } else if (bid < SEG_CT) {
        // ---- convT2 transpose+cast ----
        int idx = (bid - SEG_F0) * 256 + tid;
        if (idx < 147456) {
            int o = idx / 1152, kk = idx - o * 1152;
            int k2 = kk >> 7, c = kk & 127;
            convT2[idx] = f2bf_rne(conv_w[o * 1152 + c * 9 + k2]);
        }
    } else {
        // ---- sampling positions, one (b,t1) per block ----
        const int bt1 = bid - SEG_CT;      // 0..485
        const int b  = bt1 / 243, t1 = bt1 - b * 243;
        const int t2 = t1 / 27,  t3 = t1 - t2 * 27;
        const int n  = b * 9 + t2;
        __shared__ float logit[17][2];
        __shared__ float aw[17][2];

        if (tid < 34) {
            int p = tid >> 1, o = tid & 1;
            const float* vrow = value + ((long)bt1 * 17 + p) * 128;
            const float* wrow = w_attn + o * 128;
            float s = 0.f;
            for (int c = 0; c < 128; c += 4) {
                float4 v = *(const float4*)(vrow + c);
                float4 w = *(const float4*)(wrow + c);
                s += v.x * w.x + v.y * w.y + v.z * w.z + v.w * w.w;
            }
            logit[p][o] = s + b_attn[o];
        }
        __syncthreads();
        if (tid < 17) {
            float l0 = logit[tid][0], l1 = logit[tid][1];
            float mx = fmaxf(l0, l1);
            float e0 = expf(l0 - mx), e1 = expf(l1 - mx);
            float inv = 1.f / (e0 + e1);
            aw[tid][0] = e0 * inv; aw[tid][1] = e1 * inv;
        }
        __syncthreads();
        for (int j = tid; j < 306; j += 256) {
            int q = j >> 1, o = j & 1;
            const float* qrow = query + ((long)bt1 * 153 + q) * 128;
            const float* wrow = w_off + o * 128;
            float s = 0.f;
            for (int c = 0; c < 128; c += 4) {
                float4 v = *(const float4*)(qrow + c);
                float4 w = *(const float4*)(wrow + c);
                s += v.x * w.x + v.y * w.y + v.z * w.z + v.w * w.w;
            }
            float off = tanhf(s + b_off[o]);
            float sp = off * aw[q % 17][o];
            long kidx = (((long)n * 27 + t3) * 153 + q) * 2 + o;
            samp[kidx] = key[kidx] + sp;
        }
    }
}

// ---------------- gather + mean + blend -> new_query ----------------
__global__ __launch_bounds__(256) void gather_k(
    const unsigned short* __restrict__ Ebase,
    const float* __restrict__ samp, const float* __restrict__ query,
    const float* __restrict__ be0, const float* __restrict__ be1,
    const float* __restrict__ be2, const float* __restrict__ be3,
    float* __restrict__ nq)
{
    const int tid = threadIdx.x;
    const int pos = blockIdx.x * 8 + (tid >> 5);
    if (pos >= NPOS) return;
    const int c4 = (tid & 31) << 2;
    const int bt1 = pos / 153, q = pos - bt1 * 153;
    const int b  = bt1 / 243, t1 = bt1 - b * 243;
    const int t2 = t1 / 27,  t3 = t1 - t2 * 27;
    const int n  = b * 9 + t2;
    const long sbase = (((long)n * 27 + t3) * 153 + q) * 2;
    const float gx = samp[sbase], gy = samp[sbase + 1];

    float ax = 0.f, ay = 0.f, az = 0.f, aww = 0.f;
    const long Eoffs[4] = {E0_OFF, E1_OFF, E2_OFF, E3_OFF};
    const int Hs[4] = {96, 48, 24, 12}, Wd[4] = {72, 36, 18, 9};
    #pragma unroll
    for (int l = 0; l < 4; ++l) {
        const int H = Hs[l], W = Wd[l];
        const unsigned short* E = Ebase + Eoffs[l] + (long)n * H * W * 128 + c4;
        float ix = ((gx + 1.f) * (float)W - 1.f) * 0.5f;
        float iy = ((gy + 1.f) * (float)H - 1.f) * 0.5f;
        float fx0 = floorf(ix), fy0 = floorf(iy);
        int x0 = (int)fx0, y0 = (int)fy0;
        int x1 = x0 + 1, y1 = y0 + 1;
        float wx1 = ix - fx0, wx0 = 1.f - wx1;
        float wy1 = iy - fy0, wy0 = 1.f - wy1;
        float w00 = wy0 * wx0, w01 = wy0 * wx1, w10 = wy1 * wx0, w11 = wy1 * wx1;
        bool vy0 = (unsigned)y0 < (unsigned)H, vy1 = (unsigned)y1 < (unsigned)H;
        bool vx0 = (unsigned)x0 < (unsigned)W, vx1 = (unsigned)x1 < (unsigned)W;
        if (vy0 && vx0) { ushort4 v = *(const ushort4*)(E + ((long)y0 * W + x0) * 128);
            ax = fmaf(w00, bf2f(v.x), ax); ay = fmaf(w00, bf2f(v.y), ay);
            az = fmaf(w00, bf2f(v.z), az); aww = fmaf(w00, bf2f(v.w), aww); }
        if (vy0 && vx1) { ushort4 v = *(const ushort4*)(E + ((long)y0 * W + x1) * 128);
            ax = fmaf(w01, bf2f(v.x), ax); ay = fmaf(w01, bf2f(v.y), ay);
            az = fmaf(w01, bf2f(v.z), az); aww = fmaf(w01, bf2f(v.w), aww); }
        if (vy1 && vx0) { ushort4 v = *(const ushort4*)(E + ((long)y1 * W + x0) * 128);
            ax = fmaf(w10, bf2f(v.x), ax); ay = fmaf(w10, bf2f(v.y), ay);
            az = fmaf(w10, bf2f(v.z), az); aww = fmaf(w10, bf2f(v.w), aww); }
        if (vy1 && vx1) { ushort4 v = *(const ushort4*)(E + ((long)y1 * W + x1) * 128);
            ax = fmaf(w11, bf2f(v.x), ax); ay = fmaf(w11, bf2f(v.y), ay);
            az = fmaf(w11, bf2f(v.z), az); aww = fmaf(w11, bf2f(v.w), aww); }
    }
    float bsx = be0[c4]     + be1[c4]     + be2[c4]     + be3[c4];
    float bsy = be0[c4 + 1] + be1[c4 + 1] + be2[c4 + 1] + be3[c4 + 1];
    float bsz = be0[c4 + 2] + be1[c4 + 2] + be2[c4 + 2] + be3[c4 + 2];
    float bsw = be0[c4 + 3] + be1[c4 + 3] + be2[c4 + 3] + be3[c4 + 3];
    float mx = 0.25f * (ax + bsx), my = 0.25f * (ay + bsy);
    float mz = 0.25f * (az + bsz), mw = 0.25f * (aww + bsw);
    const long qi = ((long)bt1 * 153 + q) * 128 + c4;
    float4 qv = *(const float4*)(query + qi);
    float4 o;
    o.x = 0.1f * mx + 0.9f * qv.x;
    o.y = 0.1f * my + 0.9f * qv.y;
    o.z = 0.1f * mz + 0.9f * qv.z;
    o.w = 0.1f * mw + 0.9f * qv.w;
    *(float4*)(nq + qi) = o;
}

// ---------------- conv GEMM via bf16 MFMA ----------------
// nv[m][o] = sum_kk nq[m*1152+kk] * convT2[o][kk] + conv_b[o]
// grid (130 m-tiles, 2 n-tiles); block 256 = 4 waves (2x2 of 32x32);
// tile M=64 x N=64, BK=32; register double-buffer.
__global__ __launch_bounds__(256) void conv_mfma_k(
    const float* __restrict__ nq, const unsigned short* __restrict__ convT2,
    const float* __restrict__ conv_b, float* __restrict__ nv)
{
    __shared__ unsigned short As[64][40];   // [m][k] pad 32->40 (row 80B)
    __shared__ unsigned short Bs[64][40];   // [n][k]

    const int tid  = threadIdx.x;
    const int lane = tid & 63;
    const int wave = tid >> 6;
    const int wm = (wave & 1) * 32;
    const int wn = (wave >> 1) * 32;
    const int m0 = blockIdx.x * 64;
    const int n0 = blockIdx.y * 64;
    const int l15  = lane & 15;
    const int quad = lane >> 4;

    floatx4 acc[2][2];
    #pragma unroll
    for (int i = 0; i < 2; ++i)
        #pragma unroll
        for (int j = 0; j < 2; ++j) acc[i][j] = (floatx4){0.f, 0.f, 0.f, 0.f};

    const int am = tid >> 2;             // 0..63
    const int ak = (tid & 3) << 3;       // 0,8,16,24
    const int bn = tid & 63;             // 0..63
    const int bk = (tid >> 6) << 3;      // 0,8,16,24

    float4 a0, a1; uint4 bv;
    auto fetch = [&](int k0) {
        a0 = (float4){0,0,0,0}; a1 = (float4){0,0,0,0};
        int row = m0 + am;
        if (row < M_CONV) {
            const float* p = nq + (long)row * 1152 + k0 + ak;
            a0 = *(const float4*)p;
            a1 = *(const float4*)(p + 4);
        }
        bv = *(const uint4*)(convT2 + (long)(n0 + bn) * 1152 + k0 + bk);
    };
    fetch(0);

    for (int k0 = 0; k0 < 1152; k0 += 32) {
        unsigned short* dst = &As[am][ak];
        dst[0] = f2bf_rne(a0.x); dst[1] = f2bf_rne(a0.y);
        dst[2] = f2bf_rne(a0.z); dst[3] = f2bf_rne(a0.w);
        dst[4] = f2bf_rne(a1.x); dst[5] = f2bf_rne(a1.y);
        dst[6] = f2bf_rne(a1.z); dst[7] = f2bf_rne(a1.w);
        *(uint4*)&Bs[bn][bk] = bv;
        __syncthreads();
        if (k0 + 32 < 1152) fetch(k0 + 32);

        short8 af[2], bfr[2];
        #pragma unroll
        for (int mt = 0; mt < 2; ++mt)
            af[mt] = *(const short8*)&As[wm + mt * 16 + l15][quad * 8];
        #pragma unroll
        for (int nt = 0; nt < 2; ++nt)
            bfr[nt] = *(const short8*)&Bs[wn + nt * 16 + l15][quad * 8];
        #pragma unroll
        for (int mt = 0; mt < 2; ++mt)
            #pragma unroll
            for (int nt = 0; nt < 2; ++nt)
                acc[mt][nt] = __builtin_amdgcn_mfma_f32_16x16x32_bf16(
                    af[mt], bfr[nt], acc[mt][nt], 0, 0, 0);
        __syncthreads();
    }

    // epilogue: C/D layout col=lane&15, row=quad*4+r
    #pragma unroll
    for (int mt = 0; mt < 2; ++mt) {
        #pragma unroll
        for (int nt = 0; nt < 2; ++nt) {
            int col = n0 + wn + nt * 16 + l15;
            float bias = conv_b[col];
            #pragma unroll
            for (int r = 0; r < 4; ++r) {
                int row = m0 + wm + mt * 16 + quad * 4 + r;
                if (row < M_CONV)
                    nv[(long)row * 128 + col] = acc[mt][nt][r] + bias;
            }
        }
    }
}

extern "C" void kernel_launch(void* const* d_in, const int* in_sizes, int n_in,
                              void* d_out, int out_size, void* d_ws, size_t ws_size,
                              hipStream_t stream) {
    const float* f0     = (const float*)d_in[0];
    const float* f1     = (const float*)d_in[1];
    const float* f2     = (const float*)d_in[2];
    const float* f3     = (const float*)d_in[3];
    const float* query  = (const float*)d_in[4];
    const float* key    = (const float*)d_in[5];
    const float* value  = (const float*)d_in[6];
    const float* w_off  = (const float*)d_in[7];
    const float* b_off  = (const float*)d_in[8];
    const float* w_attn = (const float*)d_in[9];
    const float* b_attn = (const float*)d_in[10];
    const float* we0    = (const float*)d_in[11];
    const float* be0    = (const float*)d_in[12];
    const float* we1    = (const float*)d_in[13];
    const float* be1    = (const float*)d_in[14];
    const float* we2    = (const float*)d_in[15];
    const float* be2    = (const float*)d_in[16];
    const float* we3    = (const float*)d_in[17];
    const float* be3    = (const float*)d_in[18];
    const float* conv_w = (const float*)d_in[19];
    const float* conv_b = (const float*)d_in[20];

    float* out  = (float*)d_out;
    float* nq   = out;                       // new_query
    float* nv   = out + NQ_SIZE;             // new_value
    float* samp = out + NQ_SIZE + NV_SIZE;   // sampling_positions

    // ws layout: E maps (bf16, 21,150,720) | convT2 (bf16, 147,456)
    unsigned short* Ebase  = (unsigned short*)d_ws;
    unsigned short* convT2 = Ebase + E_END;

    // 1. fused prep: projections + convT2 transpose + sampling positions
    prep_k<<<PREP_GRID, 256, 0, stream>>>(
        f0, f1, f2, f3, we0, we1, we2, we3, conv_w, convT2,
        query, value, key, w_off, b_off, w_attn, b_attn, samp, Ebase);

    // 2. gather + mean + blend -> new_query
    gather_k<<<(NPOS + 7) / 8, 256, 0, stream>>>(Ebase, samp, query, be0, be1, be2, be3, nq);

    // 3. new_value GEMM via MFMA: M=8262, K=1152, N=128
    conv_mfma_k<<<dim3(130, 2), 256, 0, stream>>>(nq, convT2, conv_b, nv);
}

// Round 4
// 246.915 us; speedup vs baseline: 1.7255x; 1.0736x over previous
//
#include <hip/hip_runtime.h>
#include <hip/hip_bf16.h>

// ---------------- problem constants ----------------
// B=2 T2=9 T3=27 T1=243 P=17 K2=9 C=128
// CH = {48,96,192,384}, HW = {(96,72),(48,36),(24,18),(12,9)}, N=18
static constexpr int NQ_SIZE = 9517824;
static constexpr int NV_SIZE = 1057536;
static constexpr int NPOS    = 74358;   // 486*153 sampling points
static constexpr int M_CONV  = 8262;    // 2*243*17 rows of the conv GEMM

// E-map (projected feature, bf16, channels-last [n,h,w,128]) element offsets in ws
static constexpr long E0_OFF = 0;
static constexpr long E1_OFF = 15925248;            // 18*96*72*128
static constexpr long E2_OFF = E1_OFF + 3981312;    // 18*48*36*128
static constexpr long E3_OFF = E2_OFF + 995328;     // 18*24*18*128
static constexpr long E_END  = E3_OFF + 248832;     // 18*12*9*128  -> 21,150,720 elems

// prep kernel block-range segmentation (long-serial levels first)
static constexpr int SEG_F3  = 36;            // 2 tiles x 18
static constexpr int SEG_F2  = SEG_F3 + 126;  // 7 x 18
static constexpr int SEG_F1  = SEG_F2 + 486;  // 27 x 18
static constexpr int SEG_F0  = SEG_F1 + 1944; // 108 x 18
static constexpr int SEG_CT  = SEG_F0 + 576;  // convT2: 147456/256
static constexpr int SEG_SP  = SEG_CT + 486;  // sampos
static constexpr int PREP_GRID = SEG_SP;      // 3654

typedef __attribute__((ext_vector_type(8))) short short8;   // 8 bf16 (4 VGPRs)
typedef __attribute__((ext_vector_type(4))) float floatx4;

__device__ __forceinline__ float bf2f(unsigned short u) {
    union { unsigned int i; float f; } v; v.i = ((unsigned)u) << 16; return v.f;
}
__device__ __forceinline__ unsigned short f2bf_rne(float f) {
    union { float f; unsigned int i; } v; v.f = f;
    unsigned int u = v.i;
    u += 0x7fffu + ((u >> 16) & 1u);
    return (unsigned short)(u >> 16);
}

// ---------------- fused prep kernel ----------------
// blocks [0,SEG_F0):   projection GEMMs via bf16 MFMA:
//                      E_l[n,s,o] = sum_c f_l[n,c,s] * we_l[o,c]
//                      tile: M=64 (s) x N=128 (o), BK=32, zero-pad K to 32.
// blocks [SEG_F0,SEG_CT): convT2[o*1152+(k2*128+c)] = bf16(conv_w[o*1152+c*9+k2])
// blocks [SEG_CT,SEG_SP): sampling positions
__global__ __launch_bounds__(256) void prep_k(
    const float* __restrict__ f0, const float* __restrict__ f1,
    const float* __restrict__ f2, const float* __restrict__ f3,
    const float* __restrict__ we0, const float* __restrict__ we1,
    const float* __restrict__ we2, const float* __restrict__ we3,
    const float* __restrict__ conv_w, unsigned short* __restrict__ convT2,
    const float* __restrict__ query, const float* __restrict__ value,
    const float* __restrict__ key,
    const float* __restrict__ w_off, const float* __restrict__ b_off,
    const float* __restrict__ w_attn, const float* __restrict__ b_attn,
    float* __restrict__ samp, unsigned short* __restrict__ Ebase)
{
    const int bid = blockIdx.x;
    const int tid = threadIdx.x;

    if (bid < SEG_F0) {
        // ---- projection GEMM tile via MFMA: 64 m x 128 o, BK=32 ----
        __shared__ unsigned short As[64][40];    // [m][k], pad 32->40
        __shared__ unsigned short Bs[128][40];   // [o][k]

        const float* A; const float* W; unsigned short* Eo;
        int M, K, m0;
        if (bid < SEG_F3) {
            int n = bid >> 1, t = bid & 1;
            M = 108; K = 384; A = f3 + (long)n * 384 * 108; W = we3;
            Eo = Ebase + E3_OFF + (long)n * 108 * 128; m0 = t * 64;
        } else if (bid < SEG_F2) {
            int r = bid - SEG_F3; int n = r / 7, t = r - n * 7;
            M = 432; K = 192; A = f2 + (long)n * 192 * 432; W = we2;
            Eo = Ebase + E2_OFF + (long)n * 432 * 128; m0 = t * 64;
        } else if (bid < SEG_F1) {
            int r = bid - SEG_F2; int n = r / 27, t = r - n * 27;
            M = 1728; K = 96; A = f1 + (long)n * 96 * 1728; W = we1;
            Eo = Ebase + E1_OFF + (long)n * 1728 * 128; m0 = t * 64;
        } else {
            int r = bid - SEG_F1; int n = r / 108, t = r - n * 108;
            M = 6912; K = 48; A = f0 + (long)n * 48 * 6912; W = we0;
            Eo = Ebase + E0_OFF + (long)n * 6912 * 128; m0 = t * 64;
        }

        const int lane = tid & 63;
        const int wave = tid >> 6;
        const int wm = (wave & 1) * 32;     // 2 waves along m
        const int wn = (wave >> 1) * 64;    // 2 waves along o
        const int l15  = lane & 15;
        const int quad = lane >> 4;

        floatx4 acc[2][4];
        #pragma unroll
        for (int i = 0; i < 2; ++i)
            #pragma unroll
            for (int j = 0; j < 4; ++j) acc[i][j] = (floatx4){0.f, 0.f, 0.f, 0.f};

        // A staging: thread -> k = tid>>3 (0..31), m-group = (tid&7)*8
        const int sak = tid >> 3;
        const int sam = (tid & 7) << 3;
        // B staging: thread -> o = tid>>1 (0..127), k-half = (tid&1)*16
        const int sbo = tid >> 1;
        const int sbk = (tid & 1) << 4;

        float4 av0, av1, bv0, bv1, bv2, bv3;
        auto fetch = [&](int k0) {
            av0 = (float4){0,0,0,0}; av1 = (float4){0,0,0,0};
            if (k0 + sak < K) {
                const float* p = A + (long)(k0 + sak) * M + m0 + sam;
                if (m0 + sam + 7 < M) {
                    av0 = *(const float4*)p;
                    av1 = *(const float4*)(p + 4);
                } else if (m0 + sam < M) {
                    float tmp[8] = {0,0,0,0,0,0,0,0};
                    int nv_ = M - (m0 + sam);
                    for (int i = 0; i < 8; ++i) if (i < nv_) tmp[i] = p[i];
                    av0 = (float4){tmp[0], tmp[1], tmp[2], tmp[3]};
                    av1 = (float4){tmp[4], tmp[5], tmp[6], tmp[7]};
                }
            }
            bv0 = (float4){0,0,0,0}; bv1 = bv0; bv2 = bv0; bv3 = bv0;
            if (k0 + sbk < K) {   // K%16==0, so whole 16 valid
                const float* wp = W + (long)sbo * K + k0 + sbk;
                bv0 = *(const float4*)wp;
                bv1 = *(const float4*)(wp + 4);
                bv2 = *(const float4*)(wp + 8);
                bv3 = *(const float4*)(wp + 12);
            }
        };
        fetch(0);

        for (int k0 = 0; k0 < K; k0 += 32) {
            // A: transpose-on-write (8 scalar u16, banks ~2-way = free)
            {
                float tmp[8] = {av0.x, av0.y, av0.z, av0.w, av1.x, av1.y, av1.z, av1.w};
                #pragma unroll
                for (int i = 0; i < 8; ++i)
                    As[sam + i][sak] = f2bf_rne(tmp[i]);
            }
            // B: contiguous 16 bf16 (2 x b128 writes)
            {
                unsigned short t[16];
                float tmp[16] = {bv0.x, bv0.y, bv0.z, bv0.w, bv1.x, bv1.y, bv1.z, bv1.w,
                                 bv2.x, bv2.y, bv2.z, bv2.w, bv3.x, bv3.y, bv3.z, bv3.w};
                #pragma unroll
                for (int i = 0; i < 16; ++i) t[i] = f2bf_rne(tmp[i]);
                *(uint4*)&Bs[sbo][sbk]     = *(const uint4*)&t[0];
                *(uint4*)&Bs[sbo][sbk + 8] = *(const uint4*)&t[8];
            }
            __syncthreads();
            if (k0 + 32 < K) fetch(k0 + 32);

            short8 af[2], bfr[4];
            #pragma unroll
            for (int mt = 0; mt < 2; ++mt)
                af[mt] = *(const short8*)&As[wm + mt * 16 + l15][quad * 8];
            #pragma unroll
            for (int nt = 0; nt < 4; ++nt)
                bfr[nt] = *(const short8*)&Bs[wn + nt * 16 + l15][quad * 8];
            #pragma unroll
            for (int mt = 0; mt < 2; ++mt)
                #pragma unroll
                for (int nt = 0; nt < 4; ++nt)
                    acc[mt][nt] = __builtin_amdgcn_mfma_f32_16x16x32_bf16(
                        af[mt], bfr[nt], acc[mt][nt], 0, 0, 0);
            __syncthreads();
        }

        // epilogue: C/D col=lane&15 (o), row=quad*4+r (m)
        #pragma unroll
        for (int mt = 0; mt < 2; ++mt) {
            #pragma unroll
            for (int nt = 0; nt < 4; ++nt) {
                int col = wn + nt * 16 + l15;
                #pragma unroll
                for (int r = 0; r < 4; ++r) {
                    int m = m0 + wm + mt * 16 + quad * 4 + r;
                    if (m < M)
                        Eo[(long)m * 128 + col] = f2bf_rne(acc[mt][nt][r]);
                }
            }
        }
    } else if (bid < SEG_CT) {
        // ---- convT2 transpose+cast ----
        int idx = (bid - SEG_F0) * 256 + tid;
        if (idx < 147456) {
            int o = idx / 1152, kk = idx - o * 1152;
            int k2 = kk >> 7, c = kk & 127;
            convT2[idx] = f2bf_rne(conv_w[o * 1152 + c * 9 + k2]);
        }
    } else {
        // ---- sampling positions, one (b,t1) per block ----
        const int bt1 = bid - SEG_CT;      // 0..485
        const int b  = bt1 / 243, t1 = bt1 - b * 243;
        const int t2 = t1 / 27,  t3 = t1 - t2 * 27;
        const int n  = b * 9 + t2;
        __shared__ float logit[17][2];
        __shared__ float aw[17][2];

        if (tid < 34) {
            int p = tid >> 1, o = tid & 1;
            const float* vrow = value + ((long)bt1 * 17 + p) * 128;
            const float* wrow = w_attn + o * 128;
            float s = 0.f;
            for (int c = 0; c < 128; c += 4) {
                float4 v = *(const float4*)(vrow + c);
                float4 w = *(const float4*)(wrow + c);
                s += v.x * w.x + v.y * w.y + v.z * w.z + v.w * w.w;
            }
            logit[p][o] = s + b_attn[o];
        }
        __syncthreads();
        if (tid < 17) {
            float l0 = logit[tid][0], l1 = logit[tid][1];
            float mx = fmaxf(l0, l1);
            float e0 = expf(l0 - mx), e1 = expf(l1 - mx);
            float inv = 1.f / (e0 + e1);
            aw[tid][0] = e0 * inv; aw[tid][1] = e1 * inv;
        }
        __syncthreads();
        for (int j = tid; j < 306; j += 256) {
            int q = j >> 1, o = j & 1;
            const float* qrow = query + ((long)bt1 * 153 + q) * 128;
            const float* wrow = w_off + o * 128;
            float s = 0.f;
            for (int c = 0; c < 128; c += 4) {
                float4 v = *(const float4*)(qrow + c);
                float4 w = *(const float4*)(wrow + c);
                s += v.x * w.x + v.y * w.y + v.z * w.z + v.w * w.w;
            }
            float off = tanhf(s + b_off[o]);
            float sp = off * aw[q % 17][o];
            long kidx = (((long)n * 27 + t3) * 153 + q) * 2 + o;
            samp[kidx] = key[kidx] + sp;
        }
    }
}

// ---------------- gather + mean + blend -> new_query ----------------
__global__ __launch_bounds__(256) void gather_k(
    const unsigned short* __restrict__ Ebase,
    const float* __restrict__ samp, const float* __restrict__ query,
    const float* __restrict__ be0, const float* __restrict__ be1,
    const float* __restrict__ be2, const float* __restrict__ be3,
    float* __restrict__ nq)
{
    const int tid = threadIdx.x;
    const int pos = blockIdx.x * 8 + (tid >> 5);
    if (pos >= NPOS) return;
    const int c4 = (tid & 31) << 2;
    const int bt1 = pos / 153, q = pos - bt1 * 153;
    const int b  = bt1 / 243, t1 = bt1 - b * 243;
    const int t2 = t1 / 27,  t3 = t1 - t2 * 27;
    const int n  = b * 9 + t2;
    const long sbase = (((long)n * 27 + t3) * 153 + q) * 2;
    const float gx = samp[sbase], gy = samp[sbase + 1];

    float ax = 0.f, ay = 0.f, az = 0.f, aww = 0.f;
    const long Eoffs[4] = {E0_OFF, E1_OFF, E2_OFF, E3_OFF};
    const int Hs[4] = {96, 48, 24, 12}, Wd[4] = {72, 36, 18, 9};
    #pragma unroll
    for (int l = 0; l < 4; ++l) {
        const int H = Hs[l], W = Wd[l];
        const unsigned short* E = Ebase + Eoffs[l] + (long)n * H * W * 128 + c4;
        float ix = ((gx + 1.f) * (float)W - 1.f) * 0.5f;
        float iy = ((gy + 1.f) * (float)H - 1.f) * 0.5f;
        float fx0 = floorf(ix), fy0 = floorf(iy);
        int x0 = (int)fx0, y0 = (int)fy0;
        int x1 = x0 + 1, y1 = y0 + 1;
        float wx1 = ix - fx0, wx0 = 1.f - wx1;
        float wy1 = iy - fy0, wy0 = 1.f - wy1;
        float w00 = wy0 * wx0, w01 = wy0 * wx1, w10 = wy1 * wx0, w11 = wy1 * wx1;
        bool vy0 = (unsigned)y0 < (unsigned)H, vy1 = (unsigned)y1 < (unsigned)H;
        bool vx0 = (unsigned)x0 < (unsigned)W, vx1 = (unsigned)x1 < (unsigned)W;
        if (vy0 && vx0) { ushort4 v = *(const ushort4*)(E + ((long)y0 * W + x0) * 128);
            ax = fmaf(w00, bf2f(v.x), ax); ay = fmaf(w00, bf2f(v.y), ay);
            az = fmaf(w00, bf2f(v.z), az); aww = fmaf(w00, bf2f(v.w), aww); }
        if (vy0 && vx1) { ushort4 v = *(const ushort4*)(E + ((long)y0 * W + x1) * 128);
            ax = fmaf(w01, bf2f(v.x), ax); ay = fmaf(w01, bf2f(v.y), ay);
            az = fmaf(w01, bf2f(v.z), az); aww = fmaf(w01, bf2f(v.w), aww); }
        if (vy1 && vx0) { ushort4 v = *(const ushort4*)(E + ((long)y1 * W + x0) * 128);
            ax = fmaf(w10, bf2f(v.x), ax); ay = fmaf(w10, bf2f(v.y), ay);
            az = fmaf(w10, bf2f(v.z), az); aww = fmaf(w10, bf2f(v.w), aww); }
        if (vy1 && vx1) { ushort4 v = *(const ushort4*)(E + ((long)y1 * W + x1) * 128);
            ax = fmaf(w11, bf2f(v.x), ax); ay = fmaf(w11, bf2f(v.y), ay);
            az = fmaf(w11, bf2f(v.z), az); aww = fmaf(w11, bf2f(v.w), aww); }
    }
    float bsx = be0[c4]     + be1[c4]     + be2[c4]     + be3[c4];
    float bsy = be0[c4 + 1] + be1[c4 + 1] + be2[c4 + 1] + be3[c4 + 1];
    float bsz = be0[c4 + 2] + be1[c4 + 2] + be2[c4 + 2] + be3[c4 + 2];
    float bsw = be0[c4 + 3] + be1[c4 + 3] + be2[c4 + 3] + be3[c4 + 3];
    float mx = 0.25f * (ax + bsx), my = 0.25f * (ay + bsy);
    float mz = 0.25f * (az + bsz), mw = 0.25f * (aww + bsw);
    const long qi = ((long)bt1 * 153 + q) * 128 + c4;
    float4 qv = *(const float4*)(query + qi);
    float4 o;
    o.x = 0.1f * mx + 0.9f * qv.x;
    o.y = 0.1f * my + 0.9f * qv.y;
    o.z = 0.1f * mz + 0.9f * qv.z;
    o.w = 0.1f * mw + 0.9f * qv.w;
    *(float4*)(nq + qi) = o;
}

// ---------------- conv GEMM via bf16 MFMA ----------------
// nv[m][o] = sum_kk nq[m*1152+kk] * convT2[o][kk] + conv_b[o]
// grid (130 m-tiles, 2 n-tiles); block 256 = 4 waves (2x2 of 32x32);
// tile M=64 x N=64, BK=32; register double-buffer.
__global__ __launch_bounds__(256) void conv_mfma_k(
    const float* __restrict__ nq, const unsigned short* __restrict__ convT2,
    const float* __restrict__ conv_b, float* __restrict__ nv)
{
    __shared__ unsigned short As[64][40];   // [m][k] pad 32->40 (row 80B)
    __shared__ unsigned short Bs[64][40];   // [n][k]

    const int tid  = threadIdx.x;
    const int lane = tid & 63;
    const int wave = tid >> 6;
    const int wm = (wave & 1) * 32;
    const int wn = (wave >> 1) * 32;
    const int m0 = blockIdx.x * 64;
    const int n0 = blockIdx.y * 64;
    const int l15  = lane & 15;
    const int quad = lane >> 4;

    floatx4 acc[2][2];
    #pragma unroll
    for (int i = 0; i < 2; ++i)
        #pragma unroll
        for (int j = 0; j < 2; ++j) acc[i][j] = (floatx4){0.f, 0.f, 0.f, 0.f};

    const int am = tid >> 2;             // 0..63
    const int ak = (tid & 3) << 3;       // 0,8,16,24
    const int bn = tid & 63;             // 0..63
    const int bk = (tid >> 6) << 3;      // 0,8,16,24

    float4 a0, a1; uint4 bv;
    auto fetch = [&](int k0) {
        a0 = (float4){0,0,0,0}; a1 = (float4){0,0,0,0};
        int row = m0 + am;
        if (row < M_CONV) {
            const float* p = nq + (long)row * 1152 + k0 + ak;
            a0 = *(const float4*)p;
            a1 = *(const float4*)(p + 4);
        }
        bv = *(const uint4*)(convT2 + (long)(n0 + bn) * 1152 + k0 + bk);
    };
    fetch(0);

    for (int k0 = 0; k0 < 1152; k0 += 32) {
        unsigned short* dst = &As[am][ak];
        dst[0] = f2bf_rne(a0.x); dst[1] = f2bf_rne(a0.y);
        dst[2] = f2bf_rne(a0.z); dst[3] = f2bf_rne(a0.w);
        dst[4] = f2bf_rne(a1.x); dst[5] = f2bf_rne(a1.y);
        dst[6] = f2bf_rne(a1.z); dst[7] = f2bf_rne(a1.w);
        *(uint4*)&Bs[bn][bk] = bv;
        __syncthreads();
        if (k0 + 32 < 1152) fetch(k0 + 32);

        short8 af[2], bfr[2];
        #pragma unroll
        for (int mt = 0; mt < 2; ++mt)
            af[mt] = *(const short8*)&As[wm + mt * 16 + l15][quad * 8];
        #pragma unroll
        for (int nt = 0; nt < 2; ++nt)
            bfr[nt] = *(const short8*)&Bs[wn + nt * 16 + l15][quad * 8];
        #pragma unroll
        for (int mt = 0; mt < 2; ++mt)
            #pragma unroll
            for (int nt = 0; nt < 2; ++nt)
                acc[mt][nt] = __builtin_amdgcn_mfma_f32_16x16x32_bf16(
                    af[mt], bfr[nt], acc[mt][nt], 0, 0, 0);
        __syncthreads();
    }

    // epilogue: C/D layout col=lane&15, row=quad*4+r
    #pragma unroll
    for (int mt = 0; mt < 2; ++mt) {
        #pragma unroll
        for (int nt = 0; nt < 2; ++nt) {
            int col = n0 + wn + nt * 16 + l15;
            float bias = conv_b[col];
            #pragma unroll
            for (int r = 0; r < 4; ++r) {
                int row = m0 + wm + mt * 16 + quad * 4 + r;
                if (row < M_CONV)
                    nv[(long)row * 128 + col] = acc[mt][nt][r] + bias;
            }
        }
    }
}

extern "C" void kernel_launch(void* const* d_in, const int* in_sizes, int n_in,
                              void* d_out, int out_size, void* d_ws, size_t ws_size,
                              hipStream_t stream) {
    const float* f0     = (const float*)d_in[0];
    const float* f1     = (const float*)d_in[1];
    const float* f2     = (const float*)d_in[2];
    const float* f3     = (const float*)d_in[3];
    const float* query  = (const float*)d_in[4];
    const float* key    = (const float*)d_in[5];
    const float* value  = (const float*)d_in[6];
    const float* w_off  = (const float*)d_in[7];
    const float* b_off  = (const float*)d_in[8];
    const float* w_attn = (const float*)d_in[9];
    const float* b_attn = (const float*)d_in[10];
    const float* we0    = (const float*)d_in[11];
    const float* be0    = (const float*)d_in[12];
    const float* we1    = (const float*)d_in[13];
    const float* be1    = (const float*)d_in[14];
    const float* we2    = (const float*)d_in[15];
    const float* be2    = (const float*)d_in[16];
    const float* we3    = (const float*)d_in[17];
    const float* be3    = (const float*)d_in[18];
    const float* conv_w = (const float*)d_in[19];
    const float* conv_b = (const float*)d_in[20];

    float* out  = (float*)d_out;
    float* nq   = out;                       // new_query
    float* nv   = out + NQ_SIZE;             // new_value
    float* samp = out + NQ_SIZE + NV_SIZE;   // sampling_positions

    // ws layout: E maps (bf16, 21,150,720) | convT2 (bf16, 147,456)
    unsigned short* Ebase  = (unsigned short*)d_ws;
    unsigned short* convT2 = Ebase + E_END;

    // 1. fused prep: projections (MFMA) + convT2 transpose + sampling positions
    prep_k<<<PREP_GRID, 256, 0, stream>>>(
        f0, f1, f2, f3, we0, we1, we2, we3, conv_w, convT2,
        query, value, key, w_off, b_off, w_attn, b_attn, samp, Ebase);

    // 2. gather + mean + blend -> new_query
    gather_k<<<(NPOS + 7) / 8, 256, 0, stream>>>(Ebase, samp, query, be0, be1, be2, be3, nq);

    // 3. new_value GEMM via MFMA: M=8262, K=1152, N=128
    conv_mfma_k<<<dim3(130, 2), 256, 0, stream>>>(nq, convT2, conv_b, nv);
}